// Round 3
// baseline (843.553 us; speedup 1.0000x reference)
//
#include <hip/hip_runtime.h>

// voltageNN R5: split each (layer,batch) recurrence across 4 waves (1 per SIMD).
// Lane owns one h-element (4 gates + cell + tanh + projection partial):
// per-wave per-step issue drops ~4x (esp. the quarter-rate exp2/rcp pipe),
// and 2560 resident waves (~2.5/SIMD) fill dependency stalls.
// Scalar h allreduce: 6-DPP wave sum -> lane63 writes LDS partial ->
// __syncthreads -> ds_read_b128 broadcast of 4 partials (parity double-buffer,
// 1 barrier/step). MLP head folded into l==4 workgroups via LDS sx[t].

#define LAYERS 5
#define TT 1000
#define BATCH 128
#define CH 40            // chunk length (divides TT)
#define NCH (TT / CH)    // 25 chunks

#define LOG2E 1.4426950408889634f

__device__ __forceinline__ float fast_exp2(float x) {
#if __has_builtin(__builtin_amdgcn_exp2f)
  return __builtin_amdgcn_exp2f(x);
#else
  return __exp2f(x);
#endif
}
__device__ __forceinline__ float fast_rcp(float x) {
#if __has_builtin(__builtin_amdgcn_rcpf)
  return __builtin_amdgcn_rcpf(x);
#else
  return 1.0f / x;
#endif
}
// sigmoid for the MLP head (unscaled weights there)
__device__ __forceinline__ float fast_sigmoid(float z) {
  float e = fast_exp2(-LOG2E * z);
  return fast_rcp(1.0f + e);
}

template <int CTRL>
__device__ __forceinline__ float dpp_add(float v) {
  int moved = __builtin_amdgcn_update_dpp(0, __builtin_bit_cast(int, v),
                                          CTRL, 0xF, 0xF, false);
  return v + __builtin_bit_cast(float, moved);
}

// Wave64 sum; result valid in lanes 48..63 (row_ror 8/4/2/1 -> row sums,
// row_bcast15/31 fold rows upward).
__device__ __forceinline__ float wave_sum_hi(float v) {
  v = dpp_add<0x128>(v);  // row_ror:8
  v = dpp_add<0x124>(v);  // row_ror:4
  v = dpp_add<0x122>(v);  // row_ror:2
  v = dpp_add<0x121>(v);  // row_ror:1
  v = dpp_add<0x142>(v);  // row_bcast:15
  v = dpp_add<0x143>(v);  // row_bcast:31
  return v;
}

__device__ __forceinline__ float lane_bcast(float v, int s) {
  return __builtin_bit_cast(float, __builtin_amdgcn_readlane(__builtin_bit_cast(int, v), s));
}

__global__ __launch_bounds__(256) void lstm_fused_kernel(
    const float* __restrict__ x,     // [B, T]
    const float* __restrict__ Wih,   // [L, 1024]
    const float* __restrict__ Whh,   // [L, 1024]
    const float* __restrict__ bih,   // [L, 1024]
    const float* __restrict__ bhh,   // [L, 1024]
    const float* __restrict__ Whr,   // [L, 256]
    const float* __restrict__ W1, const float* __restrict__ b1,
    const float* __restrict__ W2, const float* __restrict__ b2,
    const float* __restrict__ W3, const float* __restrict__ b3,
    const float* __restrict__ W4, const float* __restrict__ b4,
    float* __restrict__ out,         // [B] final output
    float* __restrict__ seq,         // [L, B, T] layer outputs (workspace)
    int* __restrict__ flags)         // [L, B] chunk progress counters
{
  __shared__ __align__(16) float part[2][4];  // per-step parity double buffer
  __shared__ float sx[TT];    // l==4 only: full h sequence for the head
  __shared__ float sh[100];
  __shared__ float sh2[100];
  __shared__ float partm[100];
  __shared__ float red[4];

  const int bid  = blockIdx.x;
  const int l    = bid >> 7;   // bid / 128
  const int b    = bid & 127;  // bid % 128
  const int tid  = threadIdx.x;
  const int wid  = tid >> 6;   // wave 0..3 (one per SIMD)
  const int lane = tid & 63;
  const int e    = tid;        // h-element 0..255 owned by this lane

  // per-lane weights, pre-scaled into the exp2 domain.
  // gate order: 0=i, 1=f, 2=g(tanh), 3=o.  sc = -log2e (sigmoid), -2log2e (tanh).
  float wix[4], whx[4], gb[4];
  const int base = l * 1024;
#pragma unroll
  for (int g = 0; g < 4; ++g) {
    const float sc = (g == 2) ? (-2.0f * LOG2E) : (-LOG2E);
    int j = base + g * 256 + e;
    wix[g] = Wih[j] * sc;
    whx[g] = Whh[j] * sc;
    gb[g]  = (bih[j] + bhh[j]) * sc;
  }
  const float whr = Whr[l * 256 + e];
  float cc = 0.0f;  // scaled cell state: cc = -2*log2e * c

  const float* in   = (l == 0) ? (x + b * TT) : (seq + ((l - 1) * BATCH + b) * TT);
  float*       outp = seq + (l * BATCH + b) * TT;
  int*       my_flag = flags + l * BATCH + b;
  const int* in_flag = (l > 0) ? (flags + (l - 1) * BATCH + b) : (const int*)flags;

  const float M4 = -4.0f * LOG2E;
  const float P2 =  2.0f * LOG2E;

  float h = 0.0f;
  for (int c = 0; c < NCH; ++c) {
    if (l > 0) {
      // every wave acquires independently (preserves per-wave acquire semantics)
      while (__hip_atomic_load(in_flag, __ATOMIC_ACQUIRE,
                               __HIP_MEMORY_SCOPE_AGENT) <= c)
        __builtin_amdgcn_s_sleep(2);
    }
    float xv = 0.0f;
    if (lane < CH) {
      xv = (l == 0) ? in[c * CH + lane]
                    : __hip_atomic_load(in + c * CH + lane, __ATOMIC_RELAXED,
                                        __HIP_MEMORY_SCOPE_AGENT);
    }

    float outv = 0.0f;
#pragma unroll 2
    for (int s = 0; s < CH; ++s) {
      const float xs = lane_bcast(xv, s);

      // 4 pre-activations (one gate each, this lane's h-element)
      float p0 = fmaf(h, whx[0], fmaf(xs, wix[0], gb[0]));
      float p1 = fmaf(h, whx[1], fmaf(xs, wix[1], gb[1]));
      float p2 = fmaf(h, whx[2], fmaf(xs, wix[2], gb[2]));
      float p3 = fmaf(h, whx[3], fmaf(xs, wix[3], gb[3]));
      float E0 = fast_exp2(p0), E1 = fast_exp2(p1);
      float E2 = fast_exp2(p2), E3 = fast_exp2(p3);
      float R0 = fast_rcp(1.0f + E0);   // i
      float R1 = fast_rcp(1.0f + E1);   // f
      float R2 = fast_rcp(1.0f + E2);   // sig(2*a_g)
      float R3 = fast_rcp(1.0f + E3);   // o
      float gsc = fmaf(M4, R2, P2);     // -2log2e * tanh(a_g)
      cc = fmaf(R1, cc, R0 * gsc);      // scaled cell update
      float tR = fast_rcp(1.0f + fast_exp2(cc));
      float ow = R3 * whr;
      float r  = fmaf(ow + ow, tR, -ow);  // o * tanh(c) * whr

      // cross-wave scalar allreduce
      float v = wave_sum_hi(r);
      const int pr = s & 1;
      if (lane == 63) part[pr][wid] = v;
      __syncthreads();
      const float4 pp = *(const float4*)part[pr];   // same-addr broadcast read
      h = (pp.x + pp.y) + (pp.z + pp.w);

      if (wid == 0 && lane == s) outv = h;
      if (l == 4 && tid == 0) sx[c * CH + s] = h;   // feed the fused head
    }

    if (l < 4 && wid == 0) {
      if (lane < CH)
        __hip_atomic_store(outp + c * CH + lane, outv, __ATOMIC_RELAXED,
                           __HIP_MEMORY_SCOPE_AGENT);
      if (lane == 0)
        __hip_atomic_store(my_flag, c + 1, __ATOMIC_RELEASE,
                           __HIP_MEMORY_SCOPE_AGENT);
    }
  }

  if (l != 4) return;

  // ---------------- fused MLP head (256 threads, input in sx) ----------------
  __syncthreads();

  // phase 1: 2 threads per output (tid<100: t in [0,500); tid in [128,228): [500,1000))
  const int half = (tid >= 128) ? 1 : 0;
  const int oid  = half ? (tid - 128) : tid;
  float myacc = 0.0f;
  if (oid < 100) {
    const float* w  = W1 + oid * TT + half * 500;
    const float* xx = sx + half * 500;
    float a0 = 0.f, a1 = 0.f, a2 = 0.f, a3 = 0.f;
    for (int t0 = 0; t0 < 500; t0 += 4) {
      float4 v = *(const float4*)(w + t0);
      a0 = fmaf(v.x, xx[t0 + 0], a0);
      a1 = fmaf(v.y, xx[t0 + 1], a1);
      a2 = fmaf(v.z, xx[t0 + 2], a2);
      a3 = fmaf(v.w, xx[t0 + 3], a3);
    }
    myacc = (a0 + a1) + (a2 + a3);
    if (half) partm[oid] = myacc;
  }
  __syncthreads();
  if (tid < 100) sh[tid] = fast_sigmoid(myacc + partm[tid] + b1[tid]);
  __syncthreads();

  if (tid < 100) {
    float acc = b2[tid];
    const float* w = W2 + tid * 100;
    for (int k = 0; k < 100; ++k) acc += w[k] * sh[k];
    sh2[tid] = fast_sigmoid(acc);
  }
  __syncthreads();

  if (tid < 100) {
    float acc = b3[tid];
    const float* w = W3 + tid * 100;
    for (int k = 0; k < 100; ++k) acc += w[k] * sh2[k];
    sh[tid] = fmaxf(acc, 0.0f);
  }
  __syncthreads();

  float r = (tid < 100) ? sh[tid] * W4[tid] : 0.0f;
  r = dpp_add<0x128>(r);
  r = dpp_add<0x124>(r);
  r = dpp_add<0x122>(r);
  r = dpp_add<0x121>(r);
  r = dpp_add<0x142>(r);
  r = dpp_add<0x143>(r);
  r = __builtin_bit_cast(float, __builtin_amdgcn_readlane(__builtin_bit_cast(int, r), 63));
  if ((tid & 63) == 0) red[tid >> 6] = r;
  __syncthreads();
  if (tid == 0) out[b] = (red[0] + red[1]) + (red[2] + red[3]) + b4[0];
}

extern "C" void kernel_launch(void* const* d_in, const int* in_sizes, int n_in,
                              void* d_out, int out_size, void* d_ws, size_t ws_size,
                              hipStream_t stream) {
  const float* x   = (const float*)d_in[0];
  const float* Wih = (const float*)d_in[1];
  const float* Whh = (const float*)d_in[2];
  const float* bih = (const float*)d_in[3];
  const float* bhh = (const float*)d_in[4];
  const float* Whr = (const float*)d_in[5];
  const float* W1  = (const float*)d_in[6];
  const float* b1  = (const float*)d_in[7];
  const float* W2  = (const float*)d_in[8];
  const float* b2  = (const float*)d_in[9];
  const float* W3  = (const float*)d_in[10];
  const float* b3  = (const float*)d_in[11];
  const float* W4  = (const float*)d_in[12];
  const float* b4  = (const float*)d_in[13];

  float* seq   = (float*)d_ws;                       // [5][128][1000] f32
  int*   flags = (int*)(seq + LAYERS * BATCH * TT);  // [5][128] int

  hipMemsetAsync(flags, 0, LAYERS * BATCH * sizeof(int), stream);
  lstm_fused_kernel<<<LAYERS * BATCH, 256, 0, stream>>>(
      x, Wih, Whh, bih, bhh, Whr, W1, b1, W2, b2, W3, b3, W4, b4,
      (float*)d_out, seq, flags);
}

// Round 4
// 602.098 us; speedup vs baseline: 1.4010x; 1.4010x over previous
//
#include <hip/hip_runtime.h>

// voltageNN R6: revert to proven R4 single-wave-per-(layer,batch) structure
// (R5's cross-wave split added ~500 cyc/step of barrier+LDS latency to the
// recurrence chain and regressed 492->800 us).
// Changes vs R4:
//  1. __launch_bounds__(64, 1): R4's VGPR=40 shows the compiler allocated for
//     default occupancy and serialized the 16 independent gate pipelines.
//     One wave per SIMD may use up to 512 VGPRs -- give the scheduler room to
//     keep all exp2/rcp chains in flight and pack issue into the drains.
//  2. MLP head fused into the l==4 blocks (h streamed into LDS sx[t] by
//     lane 0); kills the second launch + seq4 global round-trip (~40-75 us
//     tail in R4).

#define LAYERS 5
#define TT 1000
#define BATCH 128
#define CH 40            // chunk length (divides TT)
#define NCH (TT / CH)    // 25 chunks

#define LOG2E 1.4426950408889634f

__device__ __forceinline__ float fast_exp2(float x) {
#if __has_builtin(__builtin_amdgcn_exp2f)
  return __builtin_amdgcn_exp2f(x);
#else
  return __exp2f(x);
#endif
}
__device__ __forceinline__ float fast_rcp(float x) {
#if __has_builtin(__builtin_amdgcn_rcpf)
  return __builtin_amdgcn_rcpf(x);
#else
  return 1.0f / x;
#endif
}
// sigmoid for the MLP head (unscaled weights there)
__device__ __forceinline__ float fast_sigmoid(float z) {
  float e = fast_exp2(-LOG2E * z);
  return fast_rcp(1.0f + e);
}

template <int CTRL>
__device__ __forceinline__ float dpp_add(float v) {
  int moved = __builtin_amdgcn_update_dpp(0, __builtin_bit_cast(int, v),
                                          CTRL, 0xF, 0xF, false);
  return v + __builtin_bit_cast(float, moved);
}

// Wave64 total, returned wave-uniform (SGPR via readlane 63).
__device__ __forceinline__ float wave_sum_uniform(float v) {
  v = dpp_add<0x128>(v);  // row_ror:8
  v = dpp_add<0x124>(v);  // row_ror:4
  v = dpp_add<0x122>(v);  // row_ror:2
  v = dpp_add<0x121>(v);  // row_ror:1
  v = dpp_add<0x142>(v);  // row_bcast:15
  v = dpp_add<0x143>(v);  // row_bcast:31
  return __builtin_bit_cast(float, __builtin_amdgcn_readlane(__builtin_bit_cast(int, v), 63));
}

__device__ __forceinline__ float lane_bcast(float v, int s) {
  return __builtin_bit_cast(float, __builtin_amdgcn_readlane(__builtin_bit_cast(int, v), s));
}

__global__ __launch_bounds__(64, 1) void lstm_wave_kernel(
    const float* __restrict__ x,     // [B, T]
    const float* __restrict__ Wih,   // [L, 1024]
    const float* __restrict__ Whh,   // [L, 1024]
    const float* __restrict__ bih,   // [L, 1024]
    const float* __restrict__ bhh,   // [L, 1024]
    const float* __restrict__ Whr,   // [L, 256]
    const float* __restrict__ W1, const float* __restrict__ b1,
    const float* __restrict__ W2, const float* __restrict__ b2,
    const float* __restrict__ W3, const float* __restrict__ b3,
    const float* __restrict__ W4, const float* __restrict__ b4,
    float* __restrict__ out,         // [B] final output
    float* __restrict__ seq,         // [L, B, T] layer outputs (workspace)
    int* __restrict__ flags)         // [L, B] chunk progress counters
{
  __shared__ float sx[TT];     // l==4 only: full h sequence for the fused head
  __shared__ float sh[104];
  __shared__ float sh2[104];

  const int bid  = blockIdx.x;
  const int l    = bid >> 7;   // bid / 128
  const int b    = bid & 127;  // bid % 128
  const int lane = threadIdx.x;

  // per-lane weights, pre-scaled into the exp2 domain.
  // gate order: 0=i, 1=f, 2=g(tanh), 3=o.  E[g] = exp2(sc*(pre-activation))
  // with sc = -log2e for sigmoid gates, -2log2e for the tanh gate.
  float wix[4][4], whx[4][4], gb[4][4], whr[4], cc[4];
  const int base = l * 1024;
#pragma unroll
  for (int g = 0; g < 4; ++g) {
    const float sc = (g == 2) ? (-2.0f * LOG2E) : (-LOG2E);
#pragma unroll
    for (int k = 0; k < 4; ++k) {
      int j = base + g * 256 + k * 64 + lane;
      wix[g][k] = Wih[j] * sc;
      whx[g][k] = Whh[j] * sc;
      gb[g][k]  = (bih[j] + bhh[j]) * sc;
    }
  }
#pragma unroll
  for (int k = 0; k < 4; ++k) {
    whr[k] = Whr[l * 256 + k * 64 + lane];
    cc[k] = 0.0f;
  }

  const float* in  = (l == 0) ? (x + b * TT) : (seq + ((l - 1) * BATCH + b) * TT);
  float*       outp = seq + (l * BATCH + b) * TT;
  int*       my_flag = flags + l * BATCH + b;
  const int* in_flag = (l > 0) ? (flags + (l - 1) * BATCH + b) : (const int*)flags;

  const float M4 = -4.0f * LOG2E;
  const float P2 =  2.0f * LOG2E;

  float h = 0.0f;
  for (int c = 0; c < NCH; ++c) {
    if (l > 0) {
      while (__hip_atomic_load(in_flag, __ATOMIC_ACQUIRE,
                               __HIP_MEMORY_SCOPE_AGENT) <= c)
        __builtin_amdgcn_s_sleep(2);
    }
    float xv = 0.0f;
    if (lane < CH) {
      if (l == 0)
        xv = in[c * CH + lane];
      else
        xv = __hip_atomic_load(in + c * CH + lane, __ATOMIC_RELAXED,
                               __HIP_MEMORY_SCOPE_AGENT);
    }

    float outv = 0.0f;
#pragma unroll 2
    for (int s = 0; s < CH; ++s) {
      const float xs = lane_bcast(xv, s);

      // phase A: h-independent part of all 16 pre-activations
      float gx[4][4];
#pragma unroll
      for (int g = 0; g < 4; ++g)
#pragma unroll
        for (int k = 0; k < 4; ++k)
          gx[g][k] = fmaf(xs, wix[g][k], gb[g][k]);

      // phase B+C: one fmaf from h, then exp2 (all 16 independent)
      float E[4][4];
#pragma unroll
      for (int g = 0; g < 4; ++g)
#pragma unroll
        for (int k = 0; k < 4; ++k)
          E[g][k] = fast_exp2(fmaf(h, whx[g][k], gx[g][k]));

      // phase D: gate combines, cell update, projection partial (k's independent)
      float r0, r1, r2, r3;
      {
        float rr[4];
#pragma unroll
        for (int k = 0; k < 4; ++k) {
          float ig = fast_rcp(1.0f + E[0][k]);
          float fg = fast_rcp(1.0f + E[1][k]);
          float gg = fmaf(2.0f, fast_rcp(1.0f + E[2][k]), -1.0f);
          float og = fast_rcp(1.0f + E[3][k]);
          cc[k] = fmaf(fg, cc[k], ig * gg);
          float tE = fast_exp2(cc[k] * (-2.0f * LOG2E));
          float tc = fmaf(2.0f, fast_rcp(1.0f + tE), -1.0f);
          rr[k] = og * tc * whr[k];
        }
        r0 = rr[0]; r1 = rr[1]; r2 = rr[2]; r3 = rr[3];
      }
      float r = (r0 + r1) + (r2 + r3);

      h = wave_sum_uniform(r);     // SGPR-uniform h(t)
      if (lane == s) outv = h;
      if (l == 4 && lane == 0) sx[c * CH + s] = h;  // stream to fused head
    }

    if (l < 4) {
      if (lane < CH)
        __hip_atomic_store(outp + c * CH + lane, outv, __ATOMIC_RELAXED,
                           __HIP_MEMORY_SCOPE_AGENT);
      if (lane == 0)
        __hip_atomic_store(my_flag, c + 1, __ATOMIC_RELEASE,
                           __HIP_MEMORY_SCOPE_AGENT);
    }
    (void)outv;
  }

  if (l != 4) return;

  // ---------------- fused MLP head (64 lanes, input in sx) ----------------
  __syncthreads();  // drain lane-0 LDS writes

  // layer 1: [100 x 1000] -> sigmoid.  Lane handles outputs lane and lane+64.
#pragma unroll
  for (int oo = 0; oo < 2; ++oo) {
    const int o = lane + oo * 64;
    if (o < 100) {
      const float* w = W1 + o * TT;
      float s0 = 0.f, s1 = 0.f, s2 = 0.f, s3 = 0.f;
      for (int t = 0; t < TT; t += 4) {
        float4 v = *(const float4*)(w + t);
        s0 = fmaf(v.x, sx[t + 0], s0);
        s1 = fmaf(v.y, sx[t + 1], s1);
        s2 = fmaf(v.z, sx[t + 2], s2);
        s3 = fmaf(v.w, sx[t + 3], s3);
      }
      sh[o] = fast_sigmoid((s0 + s1) + (s2 + s3) + b1[o]);
    }
  }
  __syncthreads();

  // layer 2: [100 x 100] -> sigmoid
#pragma unroll
  for (int oo = 0; oo < 2; ++oo) {
    const int o = lane + oo * 64;
    if (o < 100) {
      const float* w = W2 + o * 100;
      float acc = b2[o];
      for (int k = 0; k < 100; k += 4) {
        float4 v = *(const float4*)(w + k);
        acc = fmaf(v.x, sh[k + 0], acc);
        acc = fmaf(v.y, sh[k + 1], acc);
        acc = fmaf(v.z, sh[k + 2], acc);
        acc = fmaf(v.w, sh[k + 3], acc);
      }
      sh2[o] = fast_sigmoid(acc);
    }
  }
  __syncthreads();

  // layer 3: [100 x 100] -> relu (into sx, sh still needed? no - safe reuse)
#pragma unroll
  for (int oo = 0; oo < 2; ++oo) {
    const int o = lane + oo * 64;
    if (o < 100) {
      const float* w = W3 + o * 100;
      float acc = b3[o];
      for (int k = 0; k < 100; k += 4) {
        float4 v = *(const float4*)(w + k);
        acc = fmaf(v.x, sh2[k + 0], acc);
        acc = fmaf(v.y, sh2[k + 1], acc);
        acc = fmaf(v.z, sh2[k + 2], acc);
        acc = fmaf(v.w, sh2[k + 3], acc);
      }
      sx[o] = fmaxf(acc, 0.0f);
    }
  }
  __syncthreads();

  // layer 4: dot with W4 [1 x 100]
  float r = 0.0f;
#pragma unroll
  for (int oo = 0; oo < 2; ++oo) {
    const int o = lane + oo * 64;
    if (o < 100) r = fmaf(sx[o], W4[o], r);
  }
  r = wave_sum_uniform(r);
  if (lane == 0) out[b] = r + b4[0];
}

extern "C" void kernel_launch(void* const* d_in, const int* in_sizes, int n_in,
                              void* d_out, int out_size, void* d_ws, size_t ws_size,
                              hipStream_t stream) {
  const float* x   = (const float*)d_in[0];
  const float* Wih = (const float*)d_in[1];
  const float* Whh = (const float*)d_in[2];
  const float* bih = (const float*)d_in[3];
  const float* bhh = (const float*)d_in[4];
  const float* Whr = (const float*)d_in[5];
  const float* W1  = (const float*)d_in[6];
  const float* b1  = (const float*)d_in[7];
  const float* W2  = (const float*)d_in[8];
  const float* b2  = (const float*)d_in[9];
  const float* W3  = (const float*)d_in[10];
  const float* b3  = (const float*)d_in[11];
  const float* W4  = (const float*)d_in[12];
  const float* b4  = (const float*)d_in[13];

  float* seq   = (float*)d_ws;                       // [5][128][1000] f32
  int*   flags = (int*)(seq + LAYERS * BATCH * TT);  // [5][128] int

  hipMemsetAsync(flags, 0, LAYERS * BATCH * sizeof(int), stream);
  lstm_wave_kernel<<<LAYERS * BATCH, 64, 0, stream>>>(
      x, Wih, Whh, bih, bhh, Whr, W1, b1, W2, b2, W3, b3, W4, b4,
      (float*)d_out, seq, flags);
}